// Round 3
// baseline (32.833 us; speedup 1.0000x reference)
//
#include <hip/hip_runtime.h>

#define BB 32
#define LL 512
#define HH 1024
#define MAXH 32
#define MAXHL 12
#define HROWS (MAXH * MAXHL)  // 384
#define RPB 4                 // rows per block == waves per block

#define NQG (LL / RPB)        // 128
#define NHG (HROWS / RPB)     // 96
#define QBLOCKS (BB * NQG)    // 4096
#define HBLOCKS (BB * NHG)    // 3072

typedef float f32x4 __attribute__((ext_vector_type(4)));

// Fused, barrier-free kernel. Each block owns 4 consecutive output rows of one
// batch; wave w resolves + copies row idx0+w. Every wave redundantly re-derives
// the segment scan (seg is 64 KB total -> L1/L2-resident); source index for the
// wave's row is resolved in-registers via a wave max-reduce. Output stores and
// enc gathers are non-temporal (write-once / read-once streams).
__global__ __launch_bounds__(256) void fused_kernel(const float* __restrict__ enc,
                                                    const int* __restrict__ seg,
                                                    float* __restrict__ out) {
    const int bid = blockIdx.x;
    const int t = threadIdx.x;
    const int w = t >> 6;     // wave id 0..3
    const int lane = t & 63;

    // decode block -> (batch, mode, first row index)
    int b, qmode, idx0;
    long long outRow0;
    if (bid < QBLOCKS) {
        b = bid >> 7;
        idx0 = (bid & (NQG - 1)) * RPB;
        qmode = 1;
        outRow0 = (long long)b * LL + idx0;
    } else {
        int hb = bid - QBLOCKS;
        b = hb / NHG;
        idx0 = (hb % NHG) * RPB;
        qmode = 0;
        outRow0 = (long long)BB * LL + (long long)b * HROWS + idx0;
    }
    const int target = idx0 + w;

    // ---- per-wave scan: each lane owns 8 consecutive seg positions ----
    int s[8];
    const int base = b * LL + lane * 8;
#pragma unroll
    for (int k = 0; k < 8; ++k) s[k] = seg[base + k];

    int last_ish = (s[7] == 1) ? 1 : 0;
    int prev_from_left = __shfl_up(last_ish, 1);
    if (lane == 0) prev_from_left = 0;

    int qc = 0, rc = 0, mstart = -1;
    {
        int ph = prev_from_left;
#pragma unroll
        for (int k = 0; k < 8; ++k) {
            int ish = (s[k] == 1);
            if (s[k] == 2) qc++;
            if (ish && !ph) { rc++; mstart = lane * 8 + k; }
            ph = ish;
        }
    }

    // inclusive wave scan of (sum, sum, max)
    int iq = qc, ir = rc, im = mstart;
#pragma unroll
    for (int off = 1; off < 64; off <<= 1) {
        int uq = __shfl_up(iq, off);
        int ur = __shfl_up(ir, off);
        int um = __shfl_up(im, off);
        if (lane >= off) {
            iq += uq;
            ir += ur;
            im = max(im, um);
        }
    }
    int exq = iq - qc;
    int exr = ir - rc;
    int exm = __shfl_up(im, 1);
    if (lane == 0) exm = -1;

    // ---- replay: find source position for THIS wave's row ----
    int found = -1;
    {
        int qpos = exq, runs = exr, last = exm, ph = prev_from_left;
#pragma unroll
        for (int k = 0; k < 8; ++k) {
            int i = lane * 8 + k;
            int ish = (s[k] == 1);
            if (ish && !ph) { runs++; last = i; }
            if (qmode) {
                if (s[k] == 2) {
                    if (qpos == target) found = i;
                    qpos++;
                }
            } else if (ish) {
                int pos = i - last;
                int rid = runs - 1;
                if (pos < MAXHL && rid < MAXH && rid * MAXHL + pos == target) found = i;
            }
            ph = ish;
        }
    }
    // broadcast: wave max-reduce
#pragma unroll
    for (int off = 32; off > 0; off >>= 1) found = max(found, __shfl_xor(found, off));

    // ---- copy this wave's row (1024 floats = 256 f32x4; 4 per lane) ----
    f32x4* dst = reinterpret_cast<f32x4*>(out + (outRow0 + w) * HH);
    if (found >= 0) {
        const f32x4* sp = reinterpret_cast<const f32x4*>(
            enc + ((long long)b * LL + found) * HH);
#pragma unroll
        for (int j = 0; j < 4; ++j) {
            f32x4 v = __builtin_nontemporal_load(sp + lane + 64 * j);
            __builtin_nontemporal_store(v, dst + lane + 64 * j);
        }
    } else {
        f32x4 z = (f32x4)(0.f);
#pragma unroll
        for (int j = 0; j < 4; ++j) __builtin_nontemporal_store(z, dst + lane + 64 * j);
    }
}

extern "C" void kernel_launch(void* const* d_in, const int* in_sizes, int n_in,
                              void* d_out, int out_size, void* d_ws, size_t ws_size,
                              hipStream_t stream) {
    const float* enc = (const float*)d_in[0];
    const int* seg = (const int*)d_in[1];
    float* out = (float*)d_out;
    fused_kernel<<<QBLOCKS + HBLOCKS, 256, 0, stream>>>(enc, seg, out);
}

// Round 4
// 24.637 us; speedup vs baseline: 1.3327x; 1.3327x over previous
//
#include <hip/hip_runtime.h>

#define BB 32
#define LL 512
#define HH 1024
#define MAXH 32
#define MAXHL 12
#define HROWS (MAXH * MAXHL)  // 384
#define RPB 8                 // rows per block

#define NQG (LL / RPB)        // 64
#define NHG (HROWS / RPB)     // 48
#define QBLOCKS (BB * NQG)    // 2048
#define HBLOCKS (BB * NHG)    // 1536

// Fused kernel, R2 structure (wave0 scans once -> LDS -> barrier -> copy),
// but the scan is ballot/scalar-mask based: lane owns positions c*64+lane,
// __ballot gives per-chunk 64-bit masks, prefix state is wave-uniform scalar
// popcounts. No shuffle chain (critical path ~150 cyc vs ~900).
__global__ __launch_bounds__(256) void fused_kernel(const float* __restrict__ enc,
                                                    const int* __restrict__ seg,
                                                    float* __restrict__ out) {
    __shared__ int s_src[RPB];
    const int bid = blockIdx.x;
    const int t = threadIdx.x;

    // decode block -> (batch, mode, first destination row)
    int b, qmode, idx0;
    long long outRow0;
    if (bid < QBLOCKS) {
        b = bid >> 6;                       // / NQG
        idx0 = (bid & (NQG - 1)) * RPB;
        qmode = 1;
        outRow0 = (long long)b * LL + idx0;
    } else {
        int hb = bid - QBLOCKS;
        b = hb / NHG;
        idx0 = (hb % NHG) * RPB;
        qmode = 0;
        outRow0 = (long long)BB * LL + (long long)b * HROWS + idx0;
    }

    if (t < 64) {
        const int lane = t;
        if (lane < RPB) s_src[lane] = -1;

        // chunk-strided ownership: lane owns positions c*64+lane
        int sv[8];
#pragma unroll
        for (int c = 0; c < 8; ++c) sv[c] = seg[b * LL + c * 64 + lane];

        unsigned long long qm[8], hm[8];
#pragma unroll
        for (int c = 0; c < 8; ++c) {
            qm[c] = __ballot(sv[c] == 2);
            hm[c] = __ballot(sv[c] == 1);
        }

        const unsigned long long lm_lt = (1ull << lane) - 1ull;
        const unsigned long long lm_le = lm_lt | (1ull << lane);

        int qbase = 0;      // q tokens in chunks < c           (wave-uniform)
        int rbase = 0;      // run starts in chunks < c         (wave-uniform)
        int lastrs = -1;    // latest run-start pos in chunks<c (wave-uniform)
        int prev_ish = 0;   // is_h of position c*64-1          (wave-uniform)

#pragma unroll
        for (int c = 0; c < 8; ++c) {
            const unsigned long long rs =
                hm[c] & ~((hm[c] << 1) | (unsigned long long)prev_ish);
            const int i = c * 64 + lane;

            if (qmode) {
                if (sv[c] == 2) {
                    int j = qbase + __popcll(qm[c] & lm_lt);
                    int d = j - idx0;
                    if (d >= 0 && d < RPB) s_src[d] = i;
                }
            } else {
                if (sv[c] == 1) {
                    unsigned long long below = rs & lm_le;
                    int rid = rbase + __popcll(below) - 1;
                    int last = below ? (c * 64 + 63 - __clzll(below)) : lastrs;
                    int pos = i - last;
                    if (pos < MAXHL && rid < MAXH) {
                        int d = rid * MAXHL + pos - idx0;
                        if (d >= 0 && d < RPB) s_src[d] = i;
                    }
                }
            }

            qbase += __popcll(qm[c]);
            rbase += __popcll(rs);
            if (rs) lastrs = c * 64 + 63 - __clzll(rs);
            prev_ish = (int)(hm[c] >> 63) & 1;
        }
    }
    __syncthreads();

    // copy RPB rows; wave w copies rows {2w, 2w+1}; lane moves 4 float4/row
    const int w = t >> 6;
    const int lane = t & 63;
    const long long encBase = (long long)b * LL * HH;
#pragma unroll
    for (int r2 = 0; r2 < RPB / 4; ++r2) {
        const int r = w * (RPB / 4) + r2;
        const int src = s_src[r];
        float4* dst = reinterpret_cast<float4*>(out + (outRow0 + r) * HH);
        if (src >= 0) {
            const float4* sp =
                reinterpret_cast<const float4*>(enc + encBase + (long long)src * HH);
#pragma unroll
            for (int j = 0; j < 4; ++j) dst[lane + 64 * j] = sp[lane + 64 * j];
        } else {
            const float4 z = make_float4(0.f, 0.f, 0.f, 0.f);
#pragma unroll
            for (int j = 0; j < 4; ++j) dst[lane + 64 * j] = z;
        }
    }
}

extern "C" void kernel_launch(void* const* d_in, const int* in_sizes, int n_in,
                              void* d_out, int out_size, void* d_ws, size_t ws_size,
                              hipStream_t stream) {
    const float* enc = (const float*)d_in[0];
    const int* seg = (const int*)d_in[1];
    float* out = (float*)d_out;
    fused_kernel<<<QBLOCKS + HBLOCKS, 256, 0, stream>>>(enc, seg, out);
}